// Round 1
// baseline (587.475 us; speedup 1.0000x reference)
//
#include <hip/hip_runtime.h>
#include <hip/hip_bf16.h>

#define T_    1024
#define TP    1028   // T + 4 (pad 2 each side)
#define IDIM_ 512

typedef __attribute__((ext_vector_type(8))) short short8;
typedef __attribute__((ext_vector_type(4))) float floatx4;

__device__ __forceinline__ unsigned short f2bf(float f) {
  union { float f; unsigned u; } x; x.f = f;
  unsigned r = x.u + 0x7FFFu + ((x.u >> 16) & 1u);
  return (unsigned short)(r >> 16);
}
__device__ __forceinline__ float bf2f(unsigned short u) {
  union { unsigned u; float f; } x; x.u = ((unsigned)u) << 16;
  return x.f;
}

// ---------------- pad + cast hs_pad (B,T,512) f32 -> (B,T+4,512) bf16, zero borders
__global__ __launch_bounds__(256) void k_pad_cast(const float* __restrict__ hs,
                                                  unsigned short* __restrict__ xp) {
  size_t i = (size_t)blockIdx.x * 256 + threadIdx.x;
  size_t e = i * 8;                       // element index, grid sized exactly
  int c = (int)(e & 511);
  size_t rb = e >> 9;
  int r = (int)(rb % TP);
  int b = (int)(rb / TP);
  int t = r - 2;
  short8 v;
  if (t >= 0 && t < T_) {
    const float* src = hs + (((size_t)b * T_ + t) << 9) + c;
    #pragma unroll
    for (int j = 0; j < 8; j++) v[j] = (short)f2bf(src[j]);
  } else {
    #pragma unroll
    for (int j = 0; j < 8; j++) v[j] = 0;
  }
  *(short8*)(xp + e) = v;
}

// ---------------- generic f32 -> bf16 cast (n multiple of 8)
__global__ __launch_bounds__(256) void k_cast(const float* __restrict__ s,
                                              unsigned short* __restrict__ d, int n8) {
  int i = blockIdx.x * 256 + threadIdx.x;
  if (i >= n8) return;
  size_t e = (size_t)i * 8;
  short8 v;
  #pragma unroll
  for (int j = 0; j < 8; j++) v[j] = (short)f2bf(s[e + j]);
  *(short8*)(d + e) = v;
}

// ---------------- m97-style bf16 GEMM: C(M,N) = A(M,K) * Bt(N,K)^T + bias
// CONV=1: A row m reads xpad + (b*TP + t)*512, b=m>>10, t=m&1023 (overlapping rows)
template<int CONV>
__global__ __launch_bounds__(256) void k_gemm_bt(
    const unsigned short* __restrict__ A, const unsigned short* __restrict__ Bt,
    const float* __restrict__ bias, unsigned short* __restrict__ C,
    int M, int N, int K) {
  __shared__ unsigned short sA[128 * 64];
  __shared__ unsigned short sB[128 * 64];
  int tid  = threadIdx.x;
  int lane = tid & 63;
  int wv   = tid >> 6;
  int wr   = wv >> 1, wc = wv & 1;
  int m0 = blockIdx.x * 128;
  int n0 = blockIdx.y * 128;
  int l15  = lane & 15;
  int l_hi = lane >> 4;

  // staging coords: issue q covers rows q*32..q*32+31 of the 128x64 tile
  int srow = (wv << 3) + (lane >> 3);   // + q*32
  int scol = (lane & 7) << 3;           // element offset in 64-wide K slice

  floatx4 acc[4][4];
  #pragma unroll
  for (int i = 0; i < 4; i++)
    #pragma unroll
    for (int j = 0; j < 4; j++) acc[i][j] = (floatx4){0.f, 0.f, 0.f, 0.f};

  for (int k0 = 0; k0 < K; k0 += 64) {
    __syncthreads();
    #pragma unroll
    for (int q = 0; q < 4; q++) {
      int r = (q << 5) + srow;
      const unsigned short* ga;
      if (CONV) {
        int m = m0 + r;
        int b = m >> 10, t = m & 1023;
        ga = A + (((size_t)b * TP + t) << 9) + (k0 + scol);
      } else {
        ga = A + (size_t)(m0 + r) * K + (k0 + scol);
      }
      __builtin_amdgcn_global_load_lds(
          (const __attribute__((address_space(1))) void*)ga,
          (__attribute__((address_space(3))) void*)(sA + (q << 11) + (wv << 9)),
          16, 0, 0);
      int nr = n0 + r; if (nr > N - 1) nr = N - 1;   // clamp for N=1600 tail tile
      const unsigned short* gb = Bt + (size_t)nr * K + (k0 + scol);
      __builtin_amdgcn_global_load_lds(
          (const __attribute__((address_space(1))) void*)gb,
          (__attribute__((address_space(3))) void*)(sB + (q << 11) + (wv << 9)),
          16, 0, 0);
    }
    __syncthreads();
    #pragma unroll
    for (int ks = 0; ks < 2; ks++) {
      short8 af[4], bfr[4];
      #pragma unroll
      for (int i = 0; i < 4; i++) {
        af[i]  = *(const short8*)(sA + (((wr << 6) + (i << 4) + l15) << 6) + (ks << 5) + (l_hi << 3));
        bfr[i] = *(const short8*)(sB + (((wc << 6) + (i << 4) + l15) << 6) + (ks << 5) + (l_hi << 3));
      }
      #pragma unroll
      for (int i = 0; i < 4; i++)
        #pragma unroll
        for (int j = 0; j < 4; j++)
          acc[i][j] = __builtin_amdgcn_mfma_f32_16x16x32_bf16(af[i], bfr[j], acc[i][j], 0, 0, 0);
    }
  }
  #pragma unroll
  for (int i = 0; i < 4; i++) {
    int row = m0 + (wr << 6) + (i << 4) + (l_hi << 2);
    #pragma unroll
    for (int j = 0; j < 4; j++) {
      int col = n0 + (wc << 6) + (j << 4) + l15;
      if (col < N) {
        float bv = bias[col];
        #pragma unroll
        for (int jj = 0; jj < 4; jj++) {
          float v = acc[i][j][jj] + bv;
          C[(size_t)(row + jj) * N + col] = f2bf(v);
        }
      }
    }
  }
}

// ---------------- fused epilogue: per row (b,t):
// lp = log_softmax(phone_out row, 200); group-8 log_softmax of W row;
// bins[pal[a]] += exp(lp[phn[a]] + alloW[a]); out = log(bins)
__global__ __launch_bounds__(256) void k_epilogue(
    const unsigned short* __restrict__ Wm, const float* __restrict__ po,
    const int* __restrict__ phn, const int* __restrict__ pal,
    float* __restrict__ out) {
  __shared__ int   sphn[1600];
  __shared__ int   spal[1600];
  __shared__ float slp[4][200];
  __shared__ float sbin[4][100];
  int tid = threadIdx.x;
  int lane = tid & 63;
  int wv = tid >> 6;
  for (int i = tid; i < 1600; i += 256) { sphn[i] = phn[i]; spal[i] = pal[i]; }
  int m = blockIdx.x * 4 + wv;

  const float* porow = po + (size_t)m * 200;
  float v[4];
  float mx = -1e30f;
  #pragma unroll
  for (int gi = 0; gi < 4; gi++) {
    int g = lane + gi * 64;
    v[gi] = (g < 200) ? porow[g] : -1e30f;
    mx = fmaxf(mx, v[gi]);
  }
  #pragma unroll
  for (int o = 32; o >= 1; o >>= 1) mx = fmaxf(mx, __shfl_xor(mx, o));
  float s = 0.f;
  #pragma unroll
  for (int gi = 0; gi < 4; gi++) {
    int g = lane + gi * 64;
    if (g < 200) s += expf(v[gi] - mx);
  }
  #pragma unroll
  for (int o = 32; o >= 1; o >>= 1) s += __shfl_xor(s, o);
  float L = mx + logf(s);
  #pragma unroll
  for (int gi = 0; gi < 4; gi++) {
    int g = lane + gi * 64;
    if (g < 200) slp[wv][g] = v[gi] - L;
  }
  for (int p = lane; p < 100; p += 64) sbin[wv][p] = 0.f;
  __syncthreads();

  const unsigned short* wrow = Wm + (size_t)m * 1600;
  for (int g = lane; g < 200; g += 64) {
    short8 wb = *(const short8*)(wrow + g * 8);
    float w[8];
    #pragma unroll
    for (int j = 0; j < 8; j++) w[j] = bf2f((unsigned short)wb[j]);
    float gm = w[0];
    #pragma unroll
    for (int j = 1; j < 8; j++) gm = fmaxf(gm, w[j]);
    float se = 0.f;
    #pragma unroll
    for (int j = 0; j < 8; j++) se += expf(w[j] - gm);
    float gl = gm + logf(se);
    int abase = g * 8;
    #pragma unroll
    for (int j = 0; j < 8; j++) {
      int a = abase + j;
      float e = expf(slp[wv][sphn[a]] + w[j] - gl);
      atomicAdd(&sbin[wv][spal[a]], e);
    }
  }
  __syncthreads();
  float* orow = out + (size_t)m * 100;
  for (int p = lane; p < 100; p += 64) orow[p] = logf(sbin[wv][p]);
}

extern "C" void kernel_launch(void* const* d_in, const int* in_sizes, int n_in,
                              void* d_out, int out_size, void* d_ws, size_t ws_size,
                              hipStream_t stream) {
  const float* phone_out = (const float*)d_in[0];
  const float* hs  = (const float*)d_in[1];
  const float* cw  = (const float*)d_in[2];  // (512,1,5,512) -> (o, ki) row-major = B^T
  const float* cb  = (const float*)d_in[3];
  const float* w1  = (const float*)d_in[4];
  const float* b1  = (const float*)d_in[5];
  const float* w2  = (const float*)d_in[6];
  const float* b2  = (const float*)d_in[7];
  const int* phn   = (const int*)d_in[8];
  const int* pal   = (const int*)d_in[9];
  float* out = (float*)d_out;

  // workspace layout (ushorts). Wm aliases (dead) xpad+h to cap ws use at ~143 MB.
  unsigned short* ws   = (unsigned short*)d_ws;
  unsigned short* cwb  = ws;                                    //  512*2560
  unsigned short* w1b  = cwb + (size_t)512 * 2560;              //  512*512
  unsigned short* w2b  = w1b + (size_t)512 * 512;               // 1600*512
  unsigned short* h2   = w2b + (size_t)1600 * 512;              // 32768*512
  unsigned short* X    = h2  + (size_t)32768 * 512;
  unsigned short* xpad = X;                                     // 32*1028*512
  unsigned short* hbuf = X + (size_t)32 * TP * 512;             // 32768*512
  unsigned short* Wm   = X;                                     // 32768*1600 (aliases xpad,hbuf)

  k_cast<<<640, 256, 0, stream>>>(cw, cwb, 512 * 2560 / 8);
  k_cast<<<128, 256, 0, stream>>>(w1, w1b, 512 * 512 / 8);
  k_cast<<<400, 256, 0, stream>>>(w2, w2b, 1600 * 512 / 8);
  k_pad_cast<<<8224, 256, 0, stream>>>(hs, xpad);

  // conv (implicit im2col): M=32768, N=512, K=2560
  k_gemm_bt<1><<<dim3(256, 4), 256, 0, stream>>>(xpad, cwb, cb, hbuf, 32768, 512, 2560);
  // FC1: M=32768, N=512, K=512
  k_gemm_bt<0><<<dim3(256, 4), 256, 0, stream>>>(hbuf, w1b, b1, h2, 32768, 512, 512);
  // FC2: M=32768, N=1600, K=512 (13th n-tile guarded)
  k_gemm_bt<0><<<dim3(256, 13), 256, 0, stream>>>(h2, w2b, b2, Wm, 32768, 1600, 512);

  k_epilogue<<<8192, 256, 0, stream>>>(Wm, phone_out, phn, pal, out);
}

// Round 2
// 359.520 us; speedup vs baseline: 1.6341x; 1.6341x over previous
//
#include <hip/hip_runtime.h>
#include <hip/hip_bf16.h>

#define T_    1024
#define TP    1028   // T + 4 (pad 2 each side)
#define IDIM_ 512

typedef __attribute__((ext_vector_type(8))) short short8;
typedef __attribute__((ext_vector_type(4))) float floatx4;

__device__ __forceinline__ unsigned short f2bf(float f) {
  union { float f; unsigned u; } x; x.f = f;
  unsigned r = x.u + 0x7FFFu + ((x.u >> 16) & 1u);
  return (unsigned short)(r >> 16);
}
__device__ __forceinline__ float bf2f(unsigned short u) {
  union { unsigned u; float f; } x; x.u = ((unsigned)u) << 16;
  return x.f;
}

// ---------------- pad + cast hs_pad (B,T,512) f32 -> (B,T+4,512) bf16, zero borders
__global__ __launch_bounds__(256) void k_pad_cast(const float* __restrict__ hs,
                                                  unsigned short* __restrict__ xp) {
  size_t i = (size_t)blockIdx.x * 256 + threadIdx.x;
  size_t e = i * 8;
  int c = (int)(e & 511);
  size_t rb = e >> 9;
  int r = (int)(rb % TP);
  int b = (int)(rb / TP);
  int t = r - 2;
  short8 v;
  if (t >= 0 && t < T_) {
    const float* src = hs + (((size_t)b * T_ + t) << 9) + c;
    #pragma unroll
    for (int j = 0; j < 8; j++) v[j] = (short)f2bf(src[j]);
  } else {
    #pragma unroll
    for (int j = 0; j < 8; j++) v[j] = 0;
  }
  *(short8*)(xp + e) = v;
}

// ---------------- generic f32 -> bf16 cast (n multiple of 8)
__global__ __launch_bounds__(256) void k_cast(const float* __restrict__ s,
                                              unsigned short* __restrict__ d, int n8) {
  int i = blockIdx.x * 256 + threadIdx.x;
  if (i >= n8) return;
  size_t e = (size_t)i * 8;
  short8 v;
  #pragma unroll
  for (int j = 0; j < 8; j++) v[j] = (short)f2bf(s[e + j]);
  *(short8*)(d + e) = v;
}

// ---------------- transpose-cast conv_w: cw[j][ki] f32 (512 x 2560) -> cwT[ki][j] bf16
__global__ __launch_bounds__(256) void k_tcast(const float* __restrict__ cw,
                                               unsigned short* __restrict__ cwT) {
  __shared__ float tile[32][33];
  int tx = threadIdx.x & 31, ty = threadIdx.x >> 5;   // 32 x 8
  #pragma unroll
  for (int dy = 0; dy < 4; dy++) {
    int j = blockIdx.y * 32 + ty + dy * 8;
    tile[ty + dy * 8][tx] = cw[(size_t)j * 2560 + blockIdx.x * 32 + tx];
  }
  __syncthreads();
  #pragma unroll
  for (int dy = 0; dy < 4; dy++) {
    int ki = blockIdx.x * 32 + ty + dy * 8;
    cwT[(size_t)ki * 512 + blockIdx.y * 32 + tx] = f2bf(tile[tx][ty + dy * 8]);
  }
}

// ---------------- bias fold: bc[o] = b1[o] + sum_j w1[o][j] * cb[j]
__global__ __launch_bounds__(256) void k_bias_fold(const float* __restrict__ w1,
                                                   const float* __restrict__ cb,
                                                   const float* __restrict__ b1,
                                                   float* __restrict__ bc) {
  int o = blockIdx.x * 256 + threadIdx.x;
  if (o >= 512) return;
  float s = b1[o];
  for (int j = 0; j < 512; j++) s += w1[(size_t)o * 512 + j] * cb[j];
  bc[o] = s;
}

// ---------------- build inverse phoneme->arc table: inv[p*16+slot] = arc
__global__ __launch_bounds__(256) void k_build_inv(const int* __restrict__ pal,
                                                   unsigned short* __restrict__ inv) {
  __shared__ int scnt[100];
  int tid = threadIdx.x;
  if (tid < 100) scnt[tid] = 0;
  __syncthreads();
  for (int a = tid; a < 1600; a += 256) {
    int p = pal[a];
    int slot = atomicAdd(&scnt[p], 1);
    inv[p * 16 + slot] = (unsigned short)a;
  }
}

// ---------------- m97-style bf16 GEMM: C(M,N) = A(M,K) * Bt(N,K)^T [+ bias]
// CONV=1: A row m reads xpad + (b*TP + t)*512 (overlapping im2col rows)
template<int CONV, int HAS_BIAS>
__global__ __launch_bounds__(256) void k_gemm_bt(
    const unsigned short* __restrict__ A, const unsigned short* __restrict__ Bt,
    const float* __restrict__ bias, unsigned short* __restrict__ C,
    int M, int N, int K) {
  __shared__ unsigned short sA[128 * 64];
  __shared__ unsigned short sB[128 * 64];
  int tid  = threadIdx.x;
  int lane = tid & 63;
  int wv   = tid >> 6;
  int wr   = wv >> 1, wc = wv & 1;
  int m0 = blockIdx.x * 128;
  int n0 = blockIdx.y * 128;
  int l15  = lane & 15;
  int l_hi = lane >> 4;

  int srow = (wv << 3) + (lane >> 3);
  int scol = (lane & 7) << 3;

  floatx4 acc[4][4];
  #pragma unroll
  for (int i = 0; i < 4; i++)
    #pragma unroll
    for (int j = 0; j < 4; j++) acc[i][j] = (floatx4){0.f, 0.f, 0.f, 0.f};

  for (int k0 = 0; k0 < K; k0 += 64) {
    __syncthreads();
    #pragma unroll
    for (int q = 0; q < 4; q++) {
      int r = (q << 5) + srow;
      const unsigned short* ga;
      if (CONV) {
        int m = m0 + r;
        int b = m >> 10, t = m & 1023;
        ga = A + (((size_t)b * TP + t) << 9) + (k0 + scol);
      } else {
        ga = A + (size_t)(m0 + r) * K + (k0 + scol);
      }
      __builtin_amdgcn_global_load_lds(
          (const __attribute__((address_space(1))) void*)ga,
          (__attribute__((address_space(3))) void*)(sA + (q << 11) + (wv << 9)),
          16, 0, 0);
      int nr = n0 + r; if (nr > N - 1) nr = N - 1;
      const unsigned short* gb = Bt + (size_t)nr * K + (k0 + scol);
      __builtin_amdgcn_global_load_lds(
          (const __attribute__((address_space(1))) void*)gb,
          (__attribute__((address_space(3))) void*)(sB + (q << 11) + (wv << 9)),
          16, 0, 0);
    }
    __syncthreads();
    #pragma unroll
    for (int ks = 0; ks < 2; ks++) {
      short8 af[4], bfr[4];
      #pragma unroll
      for (int i = 0; i < 4; i++) {
        af[i]  = *(const short8*)(sA + (((wr << 6) + (i << 4) + l15) << 6) + (ks << 5) + (l_hi << 3));
        bfr[i] = *(const short8*)(sB + (((wc << 6) + (i << 4) + l15) << 6) + (ks << 5) + (l_hi << 3));
      }
      #pragma unroll
      for (int i = 0; i < 4; i++)
        #pragma unroll
        for (int j = 0; j < 4; j++)
          acc[i][j] = __builtin_amdgcn_mfma_f32_16x16x32_bf16(af[i], bfr[j], acc[i][j], 0, 0, 0);
    }
  }
  #pragma unroll
  for (int i = 0; i < 4; i++) {
    int row = m0 + (wr << 6) + (i << 4) + (l_hi << 2);
    #pragma unroll
    for (int j = 0; j < 4; j++) {
      int col = n0 + (wc << 6) + (j << 4) + l15;
      if (col < N) {
        float bv = HAS_BIAS ? bias[col] : 0.f;
        #pragma unroll
        for (int jj = 0; jj < 4; jj++) {
          float v = acc[i][j][jj] + bv;
          C[(size_t)(row + jj) * N + col] = f2bf(v);
        }
      }
    }
  }
}

// ---------------- fused epilogue (gather form, no atomics):
// per row: elp = softmax(phone_out); per group g: ej=exp(w-gm), se=sum;
// sarc[j][g] = elp[phn]*ej*rcp(se);  out[p] = log(sum_{a in inv[p]} sarc[a])
__global__ __launch_bounds__(256) void k_epilogue(
    const unsigned short* __restrict__ Wm, const float* __restrict__ po,
    const int* __restrict__ phn, const unsigned short* __restrict__ inv_g,
    float* __restrict__ out) {
  __shared__ unsigned short sphn[1600];
  __shared__ unsigned short sinv[1600];
  __shared__ float selp[4][200];
  __shared__ float sarc[4][1600];      // layout [j][200]: index j*200+g
  int tid = threadIdx.x;
  int lane = tid & 63;
  int wv = tid >> 6;
  for (int i = tid; i < 1600; i += 256) {
    sphn[i] = (unsigned short)phn[i];
    sinv[i] = inv_g[i];
  }
  __syncthreads();
  int m = blockIdx.x * 4 + wv;

  // phase 1: phone log-softmax -> elp = exp(lp) in LDS
  const float* porow = po + (size_t)m * 200;
  float v[4];
  float mx = -1e30f;
  #pragma unroll
  for (int gi = 0; gi < 4; gi++) {
    int g = lane + gi * 64;
    v[gi] = (g < 200) ? porow[g] : -1e30f;
    mx = fmaxf(mx, v[gi]);
  }
  #pragma unroll
  for (int o = 32; o >= 1; o >>= 1) mx = fmaxf(mx, __shfl_xor(mx, o));
  float ev[4];
  float s = 0.f;
  #pragma unroll
  for (int gi = 0; gi < 4; gi++) {
    int g = lane + gi * 64;
    if (g < 200) { ev[gi] = __expf(v[gi] - mx); s += ev[gi]; }
  }
  #pragma unroll
  for (int o = 32; o >= 1; o >>= 1) s += __shfl_xor(s, o);
  float rs = __frcp_rn(s);
  #pragma unroll
  for (int gi = 0; gi < 4; gi++) {
    int g = lane + gi * 64;
    if (g < 200) selp[wv][g] = ev[gi] * rs;
  }

  // phase 2: per-group softmax of W row, per-arc contribution into sarc
  const unsigned short* wrow = Wm + (size_t)m * 1600;
  for (int g = lane; g < 200; g += 64) {
    short8 wb = *(const short8*)(wrow + g * 8);
    float w[8];
    #pragma unroll
    for (int j = 0; j < 8; j++) w[j] = bf2f((unsigned short)wb[j]);
    float gm = w[0];
    #pragma unroll
    for (int j = 1; j < 8; j++) gm = fmaxf(gm, w[j]);
    float ej[8];
    float se = 0.f;
    #pragma unroll
    for (int j = 0; j < 8; j++) { ej[j] = __expf(w[j] - gm); se += ej[j]; }
    float rse = __frcp_rn(se);
    #pragma unroll
    for (int j = 0; j < 8; j++) {
      float e = selp[wv][sphn[g * 8 + j]] * ej[j] * rse;
      sarc[wv][j * 200 + g] = e;   // lane-consecutive per j: conflict-free
    }
  }

  // phase 3: gather per phoneme bin (all same-wave data, no barrier needed)
  float* orow = out + (size_t)m * 100;
  for (int p = lane; p < 100; p += 64) {
    const unsigned short* iv = &sinv[p * 16];
    float s2 = 0.f;
    #pragma unroll
    for (int i = 0; i < 16; i++) {
      int a = iv[i];
      s2 += sarc[wv][(a & 7) * 200 + (a >> 3)];
    }
    orow[p] = __logf(s2);
  }
}

extern "C" void kernel_launch(void* const* d_in, const int* in_sizes, int n_in,
                              void* d_out, int out_size, void* d_ws, size_t ws_size,
                              hipStream_t stream) {
  const float* phone_out = (const float*)d_in[0];
  const float* hs  = (const float*)d_in[1];
  const float* cw  = (const float*)d_in[2];  // (512,1,5,512): [out_ch][ki]
  const float* cb  = (const float*)d_in[3];
  const float* w1  = (const float*)d_in[4];
  const float* b1  = (const float*)d_in[5];
  const float* w2  = (const float*)d_in[6];
  const float* b2  = (const float*)d_in[7];
  const int* phn   = (const int*)d_in[8];
  const int* pal   = (const int*)d_in[9];
  float* out = (float*)d_out;

  // workspace layout (u16 units)
  unsigned short* ws   = (unsigned short*)d_ws;
  unsigned short* cwT  = ws;                                    // 2560*512   (cw transposed, bf16)
  unsigned short* w1b  = cwT + (size_t)2560 * 512;              //  512*512
  unsigned short* w1cw = w1b + (size_t)512 * 512;               //  512*2560  (folded conv+fc1 weight)
  unsigned short* w2b  = w1cw + (size_t)512 * 2560;             // 1600*512
  float*          bc   = (float*)(w2b + (size_t)1600 * 512);    //  512 f32
  unsigned short* inv  = (unsigned short*)(bc + 512);           // 1600 u16
  unsigned short* h2   = inv + 1664;                            // 32768*512
  unsigned short* X    = h2 + (size_t)32768 * 512;
  unsigned short* xpad = X;                                     // 32*1028*512
  unsigned short* Wm   = X;                                     // 32768*1600 (aliases dead xpad)

  k_cast<<<128, 256, 0, stream>>>(w1, w1b, 512 * 512 / 8);
  k_cast<<<400, 256, 0, stream>>>(w2, w2b, 1600 * 512 / 8);
  k_tcast<<<dim3(80, 16), 256, 0, stream>>>(cw, cwT);
  k_pad_cast<<<8224, 256, 0, stream>>>(hs, xpad);
  k_bias_fold<<<2, 256, 0, stream>>>(w1, cb, b1, bc);
  k_build_inv<<<1, 256, 0, stream>>>(pal, inv);

  // prep: w1cw[o][ki] = sum_j w1[o][j]*cw[j][ki]   (M=512, N=2560, K=512)
  k_gemm_bt<0, 0><<<dim3(4, 20), 256, 0, stream>>>(w1b, cwT, nullptr, w1cw, 512, 2560, 512);
  // G1 = conv+FC1 folded: h2 = im2col(xpad) @ w1cw^T + bc   (M=32768, N=512, K=2560)
  k_gemm_bt<1, 1><<<dim3(256, 4), 256, 0, stream>>>(xpad, w1cw, bc, h2, 32768, 512, 2560);
  // G2 = FC2: Wm = h2 @ w2^T + b2   (M=32768, N=1600, K=512)
  k_gemm_bt<0, 1><<<dim3(256, 13), 256, 0, stream>>>(h2, w2b, b2, Wm, 32768, 1600, 512);

  k_epilogue<<<8192, 256, 0, stream>>>(Wm, phone_out, phn, inv, out);
}

// Round 3
// 320.342 us; speedup vs baseline: 1.8339x; 1.1223x over previous
//
#include <hip/hip_runtime.h>
#include <hip/hip_bf16.h>

#define T_    1024
#define TP    1028   // T + 4 (pad 2 each side)
#define IDIM_ 512

typedef __attribute__((ext_vector_type(8))) short short8;
typedef __attribute__((ext_vector_type(4))) float floatx4;

__device__ __forceinline__ unsigned short f2bf(float f) {
  union { float f; unsigned u; } x; x.f = f;
  unsigned r = x.u + 0x7FFFu + ((x.u >> 16) & 1u);
  return (unsigned short)(r >> 16);
}
__device__ __forceinline__ float bf2f(unsigned short u) {
  union { unsigned u; float f; } x; x.u = ((unsigned)u) << 16;
  return x.f;
}

// ---------------- pad + cast hs_pad (B,T,512) f32 -> (B,T+4,512) bf16, zero borders
__global__ __launch_bounds__(256) void k_pad_cast(const float* __restrict__ hs,
                                                  unsigned short* __restrict__ xp) {
  size_t i = (size_t)blockIdx.x * 256 + threadIdx.x;
  size_t e = i * 8;
  int c = (int)(e & 511);
  size_t rb = e >> 9;
  int r = (int)(rb % TP);
  int b = (int)(rb / TP);
  int t = r - 2;
  short8 v;
  if (t >= 0 && t < T_) {
    const float* src = hs + (((size_t)b * T_ + t) << 9) + c;
    #pragma unroll
    for (int j = 0; j < 8; j++) v[j] = (short)f2bf(src[j]);
  } else {
    #pragma unroll
    for (int j = 0; j < 8; j++) v[j] = 0;
  }
  *(short8*)(xp + e) = v;
}

// ---------------- generic f32 -> bf16 cast (n multiple of 8)
__global__ __launch_bounds__(256) void k_cast(const float* __restrict__ s,
                                              unsigned short* __restrict__ d, int n8) {
  int i = blockIdx.x * 256 + threadIdx.x;
  if (i >= n8) return;
  size_t e = (size_t)i * 8;
  short8 v;
  #pragma unroll
  for (int j = 0; j < 8; j++) v[j] = (short)f2bf(s[e + j]);
  *(short8*)(d + e) = v;
}

// ---------------- transpose-cast conv_w: cw[j][ki] f32 (512 x 2560) -> cwT[ki][j] bf16
__global__ __launch_bounds__(256) void k_tcast(const float* __restrict__ cw,
                                               unsigned short* __restrict__ cwT) {
  __shared__ float tile[32][33];
  int tx = threadIdx.x & 31, ty = threadIdx.x >> 5;   // 32 x 8
  #pragma unroll
  for (int dy = 0; dy < 4; dy++) {
    int j = blockIdx.y * 32 + ty + dy * 8;
    tile[ty + dy * 8][tx] = cw[(size_t)j * 2560 + blockIdx.x * 32 + tx];
  }
  __syncthreads();
  #pragma unroll
  for (int dy = 0; dy < 4; dy++) {
    int ki = blockIdx.x * 32 + ty + dy * 8;
    cwT[(size_t)ki * 512 + blockIdx.y * 32 + tx] = f2bf(tile[tx][ty + dy * 8]);
  }
}

// ---------------- bias fold: bc[o] = b1[o] + sum_j w1[o][j] * cb[j]
__global__ __launch_bounds__(256) void k_bias_fold(const float* __restrict__ w1,
                                                   const float* __restrict__ cb,
                                                   const float* __restrict__ b1,
                                                   float* __restrict__ bc) {
  int o = blockIdx.x * 256 + threadIdx.x;
  if (o >= 512) return;
  float s = b1[o];
  for (int j = 0; j < 512; j++) s += w1[(size_t)o * 512 + j] * cb[j];
  bc[o] = s;
}

// ---------------- build inverse phoneme->arc table: inv[p*16+slot] = arc
__global__ __launch_bounds__(256) void k_build_inv(const int* __restrict__ pal,
                                                   unsigned short* __restrict__ inv) {
  __shared__ int scnt[100];
  int tid = threadIdx.x;
  if (tid < 100) scnt[tid] = 0;
  __syncthreads();
  for (int a = tid; a < 1600; a += 256) {
    int p = pal[a];
    int slot = atomicAdd(&scnt[p], 1);
    inv[p * 16 + slot] = (unsigned short)a;
  }
}

// ---------------- m97-style bf16 GEMM + st-style XOR swizzle (T2, both-sides):
// LDS linear layout [128 rows][64 cols] u16; data for tile-local (r,c) lives at
// (r, c ^ ((r&7)<<3)). Staging keeps LDS dest linear (global_load_lds constraint)
// and pre-swizzles the GLOBAL source column; reads apply the same involution.
// CONV=1: A row m reads xpad + (b*TP + t)*512 (overlapping im2col rows).
// Staging has NO row clamp: Bt must be allocated with rows padded to mult of 128.
template<int CONV, int HAS_BIAS>
__global__ __launch_bounds__(256) void k_gemm_bt(
    const unsigned short* __restrict__ A, const unsigned short* __restrict__ Bt,
    const float* __restrict__ bias, unsigned short* __restrict__ C,
    int M, int N, int K) {
  __shared__ unsigned short sA[128 * 64];
  __shared__ unsigned short sB[128 * 64];
  int tid  = threadIdx.x;
  int lane = tid & 63;
  int wv   = tid >> 6;
  int wr   = wv >> 1, wc = wv & 1;
  int m0 = blockIdx.x * 128;
  int n0 = blockIdx.y * 128;
  int l15  = lane & 15;
  int l_hi = lane >> 4;

  int srow = (wv << 3) + (lane >> 3);                       // + q*32
  // swizzled source column: ((lane&7) ^ (r&7))<<3, r&7 == (lane>>3)&7 -> lane-const
  int scol = (((lane & 7) ^ ((lane >> 3) & 7)) << 3);
  int rkey = (l15 & 7) << 3;                                // read-side XOR key

  floatx4 acc[4][4];
  #pragma unroll
  for (int i = 0; i < 4; i++)
    #pragma unroll
    for (int j = 0; j < 4; j++) acc[i][j] = (floatx4){0.f, 0.f, 0.f, 0.f};

  for (int k0 = 0; k0 < K; k0 += 64) {
    __syncthreads();
    #pragma unroll
    for (int q = 0; q < 4; q++) {
      int r = (q << 5) + srow;
      const unsigned short* ga;
      if (CONV) {
        int m = m0 + r;
        int b = m >> 10, t = m & 1023;
        ga = A + (((size_t)b * TP + t) << 9) + (k0 + scol);
      } else {
        ga = A + (size_t)(m0 + r) * K + (k0 + scol);
      }
      __builtin_amdgcn_global_load_lds(
          (const __attribute__((address_space(1))) void*)ga,
          (__attribute__((address_space(3))) void*)(sA + (q << 11) + (wv << 9)),
          16, 0, 0);
      const unsigned short* gb = Bt + (size_t)(n0 + r) * K + (k0 + scol);
      __builtin_amdgcn_global_load_lds(
          (const __attribute__((address_space(1))) void*)gb,
          (__attribute__((address_space(3))) void*)(sB + (q << 11) + (wv << 9)),
          16, 0, 0);
    }
    __syncthreads();
    #pragma unroll
    for (int ks = 0; ks < 2; ks++) {
      int col = ((ks << 5) + (l_hi << 3)) ^ rkey;           // swizzled read col
      short8 af[4], bfr[4];
      #pragma unroll
      for (int i = 0; i < 4; i++) {
        af[i]  = *(const short8*)(sA + (((wr << 6) + (i << 4) + l15) << 6) + col);
        bfr[i] = *(const short8*)(sB + (((wc << 6) + (i << 4) + l15) << 6) + col);
      }
      #pragma unroll
      for (int i = 0; i < 4; i++)
        #pragma unroll
        for (int j = 0; j < 4; j++)
          acc[i][j] = __builtin_amdgcn_mfma_f32_16x16x32_bf16(af[i], bfr[j], acc[i][j], 0, 0, 0);
    }
  }
  #pragma unroll
  for (int i = 0; i < 4; i++) {
    int row = m0 + (wr << 6) + (i << 4) + (l_hi << 2);
    #pragma unroll
    for (int j = 0; j < 4; j++) {
      int col = n0 + (wc << 6) + (j << 4) + l15;
      if (col < N) {
        float bv = HAS_BIAS ? bias[col] : 0.f;
        #pragma unroll
        for (int jj = 0; jj < 4; jj++) {
          float v = acc[i][j][jj] + bv;
          C[(size_t)(row + jj) * N + col] = f2bf(v);
        }
      }
    }
  }
}

// ---------------- fused epilogue (gather form, no atomics)
__global__ __launch_bounds__(256) void k_epilogue(
    const unsigned short* __restrict__ Wm, const float* __restrict__ po,
    const int* __restrict__ phn, const unsigned short* __restrict__ inv_g,
    float* __restrict__ out) {
  __shared__ unsigned short sphn[1600];
  __shared__ unsigned short sinv[1600];
  __shared__ float selp[4][200];
  __shared__ float sarc[4][1600];      // layout [j][200]: index j*200+g
  int tid = threadIdx.x;
  int lane = tid & 63;
  int wv = tid >> 6;
  for (int i = tid; i < 1600; i += 256) {
    sphn[i] = (unsigned short)phn[i];
    sinv[i] = inv_g[i];
  }
  __syncthreads();
  int m = blockIdx.x * 4 + wv;

  const float* porow = po + (size_t)m * 200;
  float v[4];
  float mx = -1e30f;
  #pragma unroll
  for (int gi = 0; gi < 4; gi++) {
    int g = lane + gi * 64;
    v[gi] = (g < 200) ? porow[g] : -1e30f;
    mx = fmaxf(mx, v[gi]);
  }
  #pragma unroll
  for (int o = 32; o >= 1; o >>= 1) mx = fmaxf(mx, __shfl_xor(mx, o));
  float ev[4];
  float s = 0.f;
  #pragma unroll
  for (int gi = 0; gi < 4; gi++) {
    int g = lane + gi * 64;
    if (g < 200) { ev[gi] = __expf(v[gi] - mx); s += ev[gi]; }
  }
  #pragma unroll
  for (int o = 32; o >= 1; o >>= 1) s += __shfl_xor(s, o);
  float rs = __frcp_rn(s);
  #pragma unroll
  for (int gi = 0; gi < 4; gi++) {
    int g = lane + gi * 64;
    if (g < 200) selp[wv][g] = ev[gi] * rs;
  }

  const unsigned short* wrow = Wm + (size_t)m * 1600;
  for (int g = lane; g < 200; g += 64) {
    short8 wb = *(const short8*)(wrow + g * 8);
    float w[8];
    #pragma unroll
    for (int j = 0; j < 8; j++) w[j] = bf2f((unsigned short)wb[j]);
    float gm = w[0];
    #pragma unroll
    for (int j = 1; j < 8; j++) gm = fmaxf(gm, w[j]);
    float ej[8];
    float se = 0.f;
    #pragma unroll
    for (int j = 0; j < 8; j++) { ej[j] = __expf(w[j] - gm); se += ej[j]; }
    float rse = __frcp_rn(se);
    #pragma unroll
    for (int j = 0; j < 8; j++) {
      float e = selp[wv][sphn[g * 8 + j]] * ej[j] * rse;
      sarc[wv][j * 200 + g] = e;   // lane-consecutive per j: conflict-free
    }
  }

  float* orow = out + (size_t)m * 100;
  for (int p = lane; p < 100; p += 64) {
    const unsigned short* iv = &sinv[p * 16];
    float s2 = 0.f;
    #pragma unroll
    for (int i = 0; i < 16; i++) {
      int a = iv[i];
      s2 += sarc[wv][(a & 7) * 200 + (a >> 3)];
    }
    orow[p] = __logf(s2);
  }
}

extern "C" void kernel_launch(void* const* d_in, const int* in_sizes, int n_in,
                              void* d_out, int out_size, void* d_ws, size_t ws_size,
                              hipStream_t stream) {
  const float* phone_out = (const float*)d_in[0];
  const float* hs  = (const float*)d_in[1];
  const float* cw  = (const float*)d_in[2];  // (512,1,5,512): [out_ch][ki]
  const float* cb  = (const float*)d_in[3];
  const float* w1  = (const float*)d_in[4];
  const float* b1  = (const float*)d_in[5];
  const float* w2  = (const float*)d_in[6];
  const float* b2  = (const float*)d_in[7];
  const int* phn   = (const int*)d_in[8];
  const int* pal   = (const int*)d_in[9];
  float* out = (float*)d_out;

  // workspace layout (u16 units). w2b padded to 1664 rows (13x128) so G2's
  // staging needs no row clamp; pad rows keep harmless 0xAAAA poison.
  unsigned short* ws   = (unsigned short*)d_ws;
  unsigned short* cwT  = ws;                                    // 2560*512
  unsigned short* w1b  = cwT + (size_t)2560 * 512;              //  512*512
  unsigned short* w1cw = w1b + (size_t)512 * 512;               //  512*2560
  unsigned short* w2b  = w1cw + (size_t)512 * 2560;             // 1664*512 (1600 used)
  float*          bc   = (float*)(w2b + (size_t)1664 * 512);    //  512 f32
  unsigned short* inv  = (unsigned short*)(bc + 512);           // 1600 u16 (+pad)
  unsigned short* h2   = inv + 1664;                            // 32768*512
  unsigned short* X    = h2 + (size_t)32768 * 512;
  unsigned short* xpad = X;                                     // 32*1028*512
  unsigned short* Wm   = X;                                     // 32768*1600 (aliases dead xpad)

  k_cast<<<128, 256, 0, stream>>>(w1, w1b, 512 * 512 / 8);
  k_cast<<<400, 256, 0, stream>>>(w2, w2b, 1600 * 512 / 8);
  k_tcast<<<dim3(80, 16), 256, 0, stream>>>(cw, cwT);
  k_pad_cast<<<8224, 256, 0, stream>>>(hs, xpad);
  k_bias_fold<<<2, 256, 0, stream>>>(w1, cb, b1, bc);
  k_build_inv<<<1, 256, 0, stream>>>(pal, inv);

  // prep: w1cw[o][ki] = sum_j w1[o][j]*cw[j][ki]   (M=512, N=2560, K=512)
  k_gemm_bt<0, 0><<<dim3(4, 20), 256, 0, stream>>>(w1b, cwT, nullptr, w1cw, 512, 2560, 512);
  // G1 = conv+FC1 folded: h2 = im2col(xpad) @ w1cw^T + bc   (M=32768, N=512, K=2560)
  k_gemm_bt<1, 1><<<dim3(256, 4), 256, 0, stream>>>(xpad, w1cw, bc, h2, 32768, 512, 2560);
  // G2 = FC2: Wm = h2 @ w2^T + b2   (M=32768, N=1600, K=512)
  k_gemm_bt<0, 1><<<dim3(256, 13), 256, 0, stream>>>(h2, w2b, b2, Wm, 32768, 1600, 512);

  k_epilogue<<<8192, 256, 0, stream>>>(Wm, phone_out, phn, inv, out);
}

// Round 4
// 273.574 us; speedup vs baseline: 2.1474x; 1.1710x over previous
//
#include <hip/hip_runtime.h>
#include <hip/hip_bf16.h>

#define T_    1024
#define TP    1028   // T + 4 (pad 2 each side)

typedef __attribute__((ext_vector_type(8))) short short8;
typedef __attribute__((ext_vector_type(4))) float floatx4;

__device__ __forceinline__ unsigned short f2bf(float f) {
  union { float f; unsigned u; } x; x.f = f;
  unsigned r = x.u + 0x7FFFu + ((x.u >> 16) & 1u);
  return (unsigned short)(r >> 16);
}
__device__ __forceinline__ float bf2f(unsigned short u) {
  union { unsigned u; float f; } x; x.u = ((unsigned)u) << 16;
  return x.f;
}

// ---------------- pad + cast hs_pad (B,T,512) f32 -> (B,T+4,512) bf16, zero borders
__global__ __launch_bounds__(256) void k_pad_cast(const float* __restrict__ hs,
                                                  unsigned short* __restrict__ xp) {
  size_t i = (size_t)blockIdx.x * 256 + threadIdx.x;
  size_t e = i * 8;
  int c = (int)(e & 511);
  size_t rb = e >> 9;
  int r = (int)(rb % TP);
  int b = (int)(rb / TP);
  int t = r - 2;
  short8 v;
  if (t >= 0 && t < T_) {
    const float* src = hs + (((size_t)b * T_ + t) << 9) + c;
    #pragma unroll
    for (int j = 0; j < 8; j++) v[j] = (short)f2bf(src[j]);
  } else {
    #pragma unroll
    for (int j = 0; j < 8; j++) v[j] = 0;
  }
  *(short8*)(xp + e) = v;
}

// ---------------- generic f32 -> bf16 cast (n multiple of 8)
__global__ __launch_bounds__(256) void k_cast(const float* __restrict__ s,
                                              unsigned short* __restrict__ d, int n8) {
  int i = blockIdx.x * 256 + threadIdx.x;
  if (i >= n8) return;
  size_t e = (size_t)i * 8;
  short8 v;
  #pragma unroll
  for (int j = 0; j < 8; j++) v[j] = (short)f2bf(s[e + j]);
  *(short8*)(d + e) = v;
}

// ---------------- transpose-cast conv_w: cw[j][ki] f32 (512 x 2560) -> cwT[ki][j] bf16
__global__ __launch_bounds__(256) void k_tcast(const float* __restrict__ cw,
                                               unsigned short* __restrict__ cwT) {
  __shared__ float tile[32][33];
  int tx = threadIdx.x & 31, ty = threadIdx.x >> 5;   // 32 x 8
  #pragma unroll
  for (int dy = 0; dy < 4; dy++) {
    int j = blockIdx.y * 32 + ty + dy * 8;
    tile[ty + dy * 8][tx] = cw[(size_t)j * 2560 + blockIdx.x * 32 + tx];
  }
  __syncthreads();
  #pragma unroll
  for (int dy = 0; dy < 4; dy++) {
    int ki = blockIdx.x * 32 + ty + dy * 8;
    cwT[(size_t)ki * 512 + blockIdx.y * 32 + tx] = f2bf(tile[tx][ty + dy * 8]);
  }
}

// ---------------- bias fold: bc[o] = b1[o] + sum_j w1[o][j] * cb[j]
__global__ __launch_bounds__(256) void k_bias_fold(const float* __restrict__ w1,
                                                   const float* __restrict__ cb,
                                                   const float* __restrict__ b1,
                                                   float* __restrict__ bc) {
  int o = blockIdx.x * 256 + threadIdx.x;
  if (o >= 512) return;
  float s = b1[o];
  for (int j = 0; j < 512; j++) s += w1[(size_t)o * 512 + j] * cb[j];
  bc[o] = s;
}

// ---------------- build inverse phoneme->arc table: inv[p*16+slot] = arc
__global__ __launch_bounds__(256) void k_build_inv(const int* __restrict__ pal,
                                                   unsigned short* __restrict__ inv) {
  __shared__ int scnt[100];
  int tid = threadIdx.x;
  if (tid < 100) scnt[tid] = 0;
  __syncthreads();
  for (int a = tid; a < 1600; a += 256) {
    int p = pal[a];
    int slot = atomicAdd(&scnt[p], 1);
    inv[p * 16 + slot] = (unsigned short)a;
  }
}

// ---------------- 128^2 2-phase GEMM (kept for the small prep GEMM only)
__global__ __launch_bounds__(256) void k_gemm_bt(
    const unsigned short* __restrict__ A, const unsigned short* __restrict__ Bt,
    unsigned short* __restrict__ C, int M, int N, int K) {
  __shared__ unsigned short sA[128 * 64];
  __shared__ unsigned short sB[128 * 64];
  int tid  = threadIdx.x;
  int lane = tid & 63;
  int wv   = tid >> 6;
  int wr   = wv >> 1, wc = wv & 1;
  int m0 = blockIdx.x * 128;
  int n0 = blockIdx.y * 128;
  int l15  = lane & 15;
  int l_hi = lane >> 4;
  int srow = (wv << 3) + (lane >> 3);
  int scol = (((lane & 7) ^ ((lane >> 3) & 7)) << 3);
  int rkey = (l15 & 7) << 3;

  floatx4 acc[4][4];
  #pragma unroll
  for (int i = 0; i < 4; i++)
    #pragma unroll
    for (int j = 0; j < 4; j++) acc[i][j] = (floatx4){0.f, 0.f, 0.f, 0.f};

  for (int k0 = 0; k0 < K; k0 += 64) {
    __syncthreads();
    #pragma unroll
    for (int q = 0; q < 4; q++) {
      int r = (q << 5) + srow;
      const unsigned short* ga = A + (size_t)(m0 + r) * K + (k0 + scol);
      __builtin_amdgcn_global_load_lds(
          (const __attribute__((address_space(1))) void*)ga,
          (__attribute__((address_space(3))) void*)(sA + (q << 11) + (wv << 9)),
          16, 0, 0);
      const unsigned short* gb = Bt + (size_t)(n0 + r) * K + (k0 + scol);
      __builtin_amdgcn_global_load_lds(
          (const __attribute__((address_space(1))) void*)gb,
          (__attribute__((address_space(3))) void*)(sB + (q << 11) + (wv << 9)),
          16, 0, 0);
    }
    __syncthreads();
    #pragma unroll
    for (int ks = 0; ks < 2; ks++) {
      int col = ((ks << 5) + (l_hi << 3)) ^ rkey;
      short8 af[4], bfr[4];
      #pragma unroll
      for (int i = 0; i < 4; i++) {
        af[i]  = *(const short8*)(sA + (((wr << 6) + (i << 4) + l15) << 6) + col);
        bfr[i] = *(const short8*)(sB + (((wc << 6) + (i << 4) + l15) << 6) + col);
      }
      #pragma unroll
      for (int i = 0; i < 4; i++)
        #pragma unroll
        for (int j = 0; j < 4; j++)
          acc[i][j] = __builtin_amdgcn_mfma_f32_16x16x32_bf16(af[i], bfr[j], acc[i][j], 0, 0, 0);
    }
  }
  #pragma unroll
  for (int i = 0; i < 4; i++) {
    int row = m0 + (wr << 6) + (i << 4) + (l_hi << 2);
    #pragma unroll
    for (int j = 0; j < 4; j++) {
      int col = n0 + (wc << 6) + (j << 4) + l15;
      #pragma unroll
      for (int jj = 0; jj < 4; jj++)
        C[(size_t)(row + jj) * N + col] = f2bf(acc[i][j][jj]);
    }
  }
}

// ---------------- 256^2 8-phase GEMM (T2+T3+T4+T5), C = A * Bt^T + bias
// LDS: 8 slots [buf][op][half] of 128x64 bf16 (16KB) = 128KB, XOR-swizzled.
// 8 waves (2M x 4N), per-wave output 128x64. 2 K-tiles (BK=64 each)/iteration.
// Stage stream (1 half-tile = 2 global_load_lds/thread per phase):
//  p1:T(t+1).A0  p2:T(t+1).A1  p3:T(t+2).B0  p4:T(t+2).B1
//  p5:T(t+2).A0  p6:T(t+2).A1  p7:T(t+3).B0  p8:T(t+3).B1
// Slot-free ledger: buf0.B read at p1,p2 (staged p3,p4); buf0.A read p1,p3
// (staged p5,p6); buf1.B read p5,p6 (staged p7,p8); buf1.A read p5,p7
// (staged next p1,p2). vmcnt(4) at p4 covers tile t+1; at p8 covers t+2.
template<int CONV>
__global__ __launch_bounds__(512, 2) void k_gemm256(
    const unsigned short* __restrict__ A, const unsigned short* __restrict__ Bt,
    const float* __restrict__ bias, unsigned short* __restrict__ C,
    int M, int N, int K) {
  __shared__ unsigned short lds[65536];   // 8 * 8192 u16
  const int tid = threadIdx.x;
  const int lane = tid & 63;
  const int w = tid >> 6;
  const int wm = w >> 2, wn = w & 3;
  const int l15 = lane & 15, l_hi = lane >> 4;
  const int rkey = (l15 & 7) << 3;
  const int m0 = blockIdx.x << 8, n0 = blockIdx.y << 8;
  const int nt = K >> 6;

  // staging per-thread setup: thread covers row (tid>>3) (+h*128+l*64), 16B chunk (tid&7)
  const int srow = tid >> 3;
  const int scol = (((tid & 7) ^ ((tid >> 3) & 7)) << 3);
  const unsigned short* abase;
  size_t astr;
  if (CONV) {
    int m = m0 + srow;                 // block never crosses a b-boundary (256 | 1024)
    int b = m >> 10, t = m & 1023;
    abase = A + (((size_t)b * TP + t) << 9) + scol;
    astr = 512;                        // im2col: +1 row = +512 elems, K-walk contiguous
  } else {
    abase = A + (size_t)(m0 + srow) * K + scol;
    astr = (size_t)K;
  }
  const unsigned short* bbase = Bt + (size_t)(n0 + srow) * K + scol;
  const size_t bstr = (size_t)K;

  #define SLOT(buf, op, h) ((((((buf) << 1) | (op)) << 1) | (h)) * 8192)

  auto STAGE = [&](int buf, int op, int h, int kt) {
    int ktc = kt < nt ? kt : nt - 1;
    const unsigned short* g0 = (op ? bbase : abase)
        + (size_t)(h * 128) * (op ? bstr : astr) + (size_t)ktc * 64;
    unsigned short* d = lds + SLOT(buf, op, h) + w * 512;
    __builtin_amdgcn_global_load_lds(
        (const __attribute__((address_space(1))) void*)g0,
        (__attribute__((address_space(3))) void*)d, 16, 0, 0);
    __builtin_amdgcn_global_load_lds(
        (const __attribute__((address_space(1))) void*)(g0 + (size_t)64 * (op ? bstr : astr)),
        (__attribute__((address_space(3))) void*)(d + 4096), 16, 0, 0);
  };

  auto RDA = [&](short8* dst, int buf, int rh) {        // 4 row-frags x 2 ks
    const unsigned short* s = lds + SLOT(buf, 0, wm);
    #pragma unroll
    for (int i = 0; i < 4; i++) {
      int row = (((rh << 2) + i) << 4) + l15;
      #pragma unroll
      for (int ks = 0; ks < 2; ks++) {
        int col = (((ks << 5) + (l_hi << 3)) ^ rkey);
        dst[i * 2 + ks] = *(const short8*)(s + (row << 6) + col);
      }
    }
  };
  auto RDB = [&](short8* dst, int buf, int jh) {        // 2 col-frags x 2 ks
    const unsigned short* s = lds + SLOT(buf, 1, (wn >> 1));
    #pragma unroll
    for (int j = 0; j < 2; j++) {
      int row = ((wn & 1) << 6) + (((jh << 1) + j) << 4) + l15;
      #pragma unroll
      for (int ks = 0; ks < 2; ks++) {
        int col = (((ks << 5) + (l_hi << 3)) ^ rkey);
        dst[j * 2 + ks] = *(const short8*)(s + (row << 6) + col);
      }
    }
  };

  floatx4 acc[8][4];
  #pragma unroll
  for (int i = 0; i < 8; i++)
    #pragma unroll
    for (int j = 0; j < 4; j++) acc[i][j] = (floatx4){0.f, 0.f, 0.f, 0.f};

  #define MMQ(ar, br, rh, ch)                                                  \
    __builtin_amdgcn_s_setprio(1);                                             \
    _Pragma("unroll")                                                          \
    for (int i = 0; i < 4; i++)                                                \
      _Pragma("unroll")                                                        \
      for (int j = 0; j < 2; j++)                                              \
        _Pragma("unroll")                                                      \
        for (int ks = 0; ks < 2; ks++)                                         \
          acc[((rh) << 2) + i][((ch) << 1) + j] =                              \
              __builtin_amdgcn_mfma_f32_16x16x32_bf16(                         \
                  ar[i * 2 + ks], br[j * 2 + ks],                              \
                  acc[((rh) << 2) + i][((ch) << 1) + j], 0, 0, 0);             \
    __builtin_amdgcn_s_setprio(0);

  // prologue: T0 fully (buf0), T1.B (buf1)
  STAGE(0, 1, 0, 0); STAGE(0, 1, 1, 0); STAGE(0, 0, 0, 0); STAGE(0, 0, 1, 0);
  STAGE(1, 1, 0, 1); STAGE(1, 1, 1, 1);
  asm volatile("s_waitcnt vmcnt(4)" ::: "memory");
  __builtin_amdgcn_s_barrier();

  short8 aR[8], bR0[4], bR1[4];
  const int niter = nt >> 1;
  for (int it = 0; it < niter; ++it) {
    const int t0 = it << 1;
    // p1: tile t0 q(0,0)
    RDA(aR, 0, 0); RDB(bR0, 0, 0);
    STAGE(1, 0, 0, t0 + 1);
    __builtin_amdgcn_s_barrier();
    MMQ(aR, bR0, 0, 0);
    __builtin_amdgcn_s_barrier();
    // p2: q(0,1)
    RDB(bR1, 0, 1);
    STAGE(1, 0, 1, t0 + 1);
    __builtin_amdgcn_s_barrier();
    MMQ(aR, bR1, 0, 1);
    __builtin_amdgcn_s_barrier();
    // p3: q(1,0)
    RDA(aR, 0, 1);
    STAGE(0, 1, 0, t0 + 2);
    __builtin_amdgcn_s_barrier();
    MMQ(aR, bR0, 1, 0);
    __builtin_amdgcn_s_barrier();
    // p4: q(1,1)  [+ tile-boundary wait]
    STAGE(0, 1, 1, t0 + 2);
    __builtin_amdgcn_s_barrier();
    MMQ(aR, bR1, 1, 1);
    asm volatile("s_waitcnt vmcnt(4)" ::: "memory");
    __builtin_amdgcn_s_barrier();
    // p5: tile t0+1 q(0,0)
    RDA(aR, 1, 0); RDB(bR0, 1, 0);
    STAGE(0, 0, 0, t0 + 2);
    __builtin_amdgcn_s_barrier();
    MMQ(aR, bR0, 0, 0);
    __builtin_amdgcn_s_barrier();
    // p6: q(0,1)
    RDB(bR1, 1, 1);
    STAGE(0, 0, 1, t0 + 2);
    __builtin_amdgcn_s_barrier();
    MMQ(aR, bR1, 0, 1);
    __builtin_amdgcn_s_barrier();
    // p7: q(1,0)
    RDA(aR, 1, 1);
    STAGE(1, 1, 0, t0 + 3);
    __builtin_amdgcn_s_barrier();
    MMQ(aR, bR0, 1, 0);
    __builtin_amdgcn_s_barrier();
    // p8: q(1,1)  [+ tile-boundary wait]
    STAGE(1, 1, 1, t0 + 3);
    __builtin_amdgcn_s_barrier();
    MMQ(aR, bR1, 1, 1);
    asm volatile("s_waitcnt vmcnt(4)" ::: "memory");
    __builtin_amdgcn_s_barrier();
  }

  #pragma unroll
  for (int i = 0; i < 8; i++) {
    int row = m0 + (wm << 7) + (i << 4) + (l_hi << 2);
    #pragma unroll
    for (int j = 0; j < 4; j++) {
      int col = n0 + (wn << 6) + (j << 4) + l15;
      if (col < N) {
        float bv = bias[col];
        #pragma unroll
        for (int jj = 0; jj < 4; jj++)
          C[(size_t)(row + jj) * N + col] = f2bf(acc[i][j][jj] + bv);
      }
    }
  }
  #undef SLOT
  #undef MMQ
}

// ---------------- fused epilogue (gather form, no atomics)
__global__ __launch_bounds__(256) void k_epilogue(
    const unsigned short* __restrict__ Wm, const float* __restrict__ po,
    const int* __restrict__ phn, const unsigned short* __restrict__ inv_g,
    float* __restrict__ out) {
  __shared__ unsigned short sphn[1600];
  __shared__ unsigned short sinv[1600];
  __shared__ float selp[4][200];
  __shared__ float sarc[4][1600];      // layout [j][200]: index j*200+g
  int tid = threadIdx.x;
  int lane = tid & 63;
  int wv = tid >> 6;
  for (int i = tid; i < 1600; i += 256) {
    sphn[i] = (unsigned short)phn[i];
    sinv[i] = inv_g[i];
  }
  __syncthreads();
  int m = blockIdx.x * 4 + wv;

  const float* porow = po + (size_t)m * 200;
  float v[4];
  float mx = -1e30f;
  #pragma unroll
  for (int gi = 0; gi < 4; gi++) {
    int g = lane + gi * 64;
    v[gi] = (g < 200) ? porow[g] : -1e30f;
    mx = fmaxf(mx, v[gi]);
  }
  #pragma unroll
  for (int o = 32; o >= 1; o >>= 1) mx = fmaxf(mx, __shfl_xor(mx, o));
  float ev[4];
  float s = 0.f;
  #pragma unroll
  for (int gi = 0; gi < 4; gi++) {
    int g = lane + gi * 64;
    if (g < 200) { ev[gi] = __expf(v[gi] - mx); s += ev[gi]; }
  }
  #pragma unroll
  for (int o = 32; o >= 1; o >>= 1) s += __shfl_xor(s, o);
  float rs = __frcp_rn(s);
  #pragma unroll
  for (int gi = 0; gi < 4; gi++) {
    int g = lane + gi * 64;
    if (g < 200) selp[wv][g] = ev[gi] * rs;
  }

  const unsigned short* wrow = Wm + (size_t)m * 1600;
  for (int g = lane; g < 200; g += 64) {
    short8 wb = *(const short8*)(wrow + g * 8);
    float w[8];
    #pragma unroll
    for (int j = 0; j < 8; j++) w[j] = bf2f((unsigned short)wb[j]);
    float gm = w[0];
    #pragma unroll
    for (int j = 1; j < 8; j++) gm = fmaxf(gm, w[j]);
    float ej[8];
    float se = 0.f;
    #pragma unroll
    for (int j = 0; j < 8; j++) { ej[j] = __expf(w[j] - gm); se += ej[j]; }
    float rse = __frcp_rn(se);
    #pragma unroll
    for (int j = 0; j < 8; j++) {
      float e = selp[wv][sphn[g * 8 + j]] * ej[j] * rse;
      sarc[wv][j * 200 + g] = e;   // lane-consecutive per j: conflict-free
    }
  }

  float* orow = out + (size_t)m * 100;
  for (int p = lane; p < 100; p += 64) {
    const unsigned short* iv = &sinv[p * 16];
    float s2 = 0.f;
    #pragma unroll
    for (int i = 0; i < 16; i++) {
      int a = iv[i];
      s2 += sarc[wv][(a & 7) * 200 + (a >> 3)];
    }
    orow[p] = __logf(s2);
  }
}

extern "C" void kernel_launch(void* const* d_in, const int* in_sizes, int n_in,
                              void* d_out, int out_size, void* d_ws, size_t ws_size,
                              hipStream_t stream) {
  const float* phone_out = (const float*)d_in[0];
  const float* hs  = (const float*)d_in[1];
  const float* cw  = (const float*)d_in[2];  // (512,1,5,512): [out_ch][ki]
  const float* cb  = (const float*)d_in[3];
  const float* w1  = (const float*)d_in[4];
  const float* b1  = (const float*)d_in[5];
  const float* w2  = (const float*)d_in[6];
  const float* b2  = (const float*)d_in[7];
  const int* phn   = (const int*)d_in[8];
  const int* pal   = (const int*)d_in[9];
  float* out = (float*)d_out;

  // workspace layout (u16 units). w2b padded to 1792 rows (7x256) for 256-wide
  // N tiles; pad rows hold harmless poison, C-write guards col<N.
  unsigned short* ws   = (unsigned short*)d_ws;
  unsigned short* cwT  = ws;                                    // 2560*512
  unsigned short* w1b  = cwT + (size_t)2560 * 512;              //  512*512
  unsigned short* w1cw = w1b + (size_t)512 * 512;               //  512*2560
  unsigned short* w2b  = w1cw + (size_t)512 * 2560;             // 1792*512 (1600 used)
  float*          bc   = (float*)(w2b + (size_t)1792 * 512);    //  512 f32
  unsigned short* inv  = (unsigned short*)(bc + 512);           // 1600 u16 (+pad)
  unsigned short* h2   = inv + 1664;                            // 32768*512
  unsigned short* X    = h2 + (size_t)32768 * 512;
  unsigned short* xpad = X;                                     // 32*1028*512
  unsigned short* Wm   = X;                                     // 32768*1600 (aliases dead xpad)

  k_cast<<<128, 256, 0, stream>>>(w1, w1b, 512 * 512 / 8);
  k_cast<<<400, 256, 0, stream>>>(w2, w2b, 1600 * 512 / 8);
  k_tcast<<<dim3(80, 16), 256, 0, stream>>>(cw, cwT);
  k_pad_cast<<<8224, 256, 0, stream>>>(hs, xpad);
  k_bias_fold<<<2, 256, 0, stream>>>(w1, cb, b1, bc);
  k_build_inv<<<1, 256, 0, stream>>>(pal, inv);

  // prep: w1cw[o][ki] = sum_j w1[o][j]*cw[j][ki]   (M=512, N=2560, K=512)
  k_gemm_bt<<<dim3(4, 20), 256, 0, stream>>>(w1b, cwT, w1cw, 512, 2560, 512);
  // G1 = conv+FC1 folded: h2 = im2col(xpad) @ w1cw^T + bc   (M=32768, N=512, K=2560)
  k_gemm256<1><<<dim3(128, 2), 512, 0, stream>>>(xpad, w1cw, bc, h2, 32768, 512, 2560);
  // G2 = FC2: Wm = h2 @ w2^T + b2   (M=32768, N=1600 pad 1792, K=512)
  k_gemm256<0><<<dim3(128, 7), 512, 0, stream>>>(h2, w2b, b2, Wm, 32768, 1600, 512);

  k_epilogue<<<8192, 256, 0, stream>>>(Wm, phone_out, phn, inv, out);
}